// Round 3
// baseline (1606.527 us; speedup 1.0000x reference)
//
#include <hip/hip_runtime.h>
#include <hip/hip_bf16.h>
#include <stdint.h>

// Fused scaled-dot-product attention with dropout (fwd), MI355X gfx950.
// B=64 heads, S=2048, D=64, fp32 in/out. Dropout mask [B,S,S] fp32 = 1 GiB
// dominates HBM traffic (floor ~195us at 6.3 TB/s achievable). Compute via
// bf16 MFMA 16x16x32: QK^T hi/lo split (3 passes, ~fp32 logits), PV bf16.
// Both MFMA operands always use the SAME k-slot bijection, so correctness
// does not depend on the hardware's internal A/B k ordering.
// R2: dropout-mask loads prefetched one full tile ahead (T14) — mask is the
// roofline stream, always HBM-cold (~900cy), and 2 blocks/CU gives thin TLP.

#define Bsz 64
#define Ssz 2048
#define Dsz 64
#define QBLK 64
#define KBLK 64
#define NT   (Ssz / KBLK)

typedef __attribute__((ext_vector_type(4))) float f32x4;
typedef __attribute__((ext_vector_type(8))) short short8;
typedef __attribute__((ext_vector_type(4))) unsigned short u16x4;

__device__ __forceinline__ unsigned short f2bf(float x) {
    unsigned u = __builtin_bit_cast(unsigned, x);
    u += 0x7FFFu + ((u >> 16) & 1u);           // RNE
    return (unsigned short)(u >> 16);
}
__device__ __forceinline__ float bf2f(unsigned short h) {
    return __builtin_bit_cast(float, (unsigned)h << 16);
}
// XOR swizzle for 128B rows: kills the 32-way bank conflict on ds_read_b128
__device__ __forceinline__ int swz(int row, int byte_in_row) {
    return row * 128 + (byte_in_row ^ ((row & 7) << 4));
}
__device__ __forceinline__ f32x4 mfma16(short8 a, short8 b, f32x4 c) {
    return __builtin_amdgcn_mfma_f32_16x16x32_bf16(a, b, c, 0, 0, 0);
}

__global__ __launch_bounds__(256, 2) void attn_fwd(
    const float* __restrict__ Q, const float* __restrict__ K,
    const float* __restrict__ V, const float* __restrict__ scale_p,
    const float* __restrict__ mask, float* __restrict__ out)
{
    __shared__ unsigned char s_khi[8192];   // K hi bf16 [64 key][64 d], swizzled
    __shared__ unsigned char s_klo[8192];   // K lo bf16
    __shared__ unsigned char s_vt [8192];   // V^T bf16 [64 d][64 key], swizzled
    __shared__ unsigned char s_p  [8192];   // P bf16 [64 q][64 key], swizzled

    // XCD-aware bijective swizzle: 2048 blocks, 8 XCDs, 256 blocks/XCD.
    // Consecutive swizzled ids (same head) land on the same XCD -> K/V L2-hit.
    const int flat = blockIdx.x;
    const int sid  = (flat & 7) * (2048 / 8) + (flat >> 3);
    const int b    = sid >> 5;            // head
    const int q0   = (sid & 31) * QBLK;   // q-block
    const int tid  = threadIdx.x;
    const int wave = tid >> 6;
    const int lane = tid & 63;
    const int c    = lane & 15;   // fragment column
    const int g    = lane >> 4;   // fragment k-group

    // exp2 domain: fold log2(e) into the scale
    const float scale = scale_p[0] * 1.44269504088896340736f;

    const float* Kb = K + (size_t)b * Ssz * Dsz;
    const float* Vb = V + (size_t)b * Ssz * Dsz;

    // ---- Q fragments, hoisted. slot(g,j) of step ks holds Q[q][ks*32+8g+j]
    short8 qh[2], ql[2];
    {
        const float* qp = Q + ((size_t)b * Ssz + (q0 + wave * 16 + c)) * Dsz + g * 8;
        #pragma unroll
        for (int ks = 0; ks < 2; ++ks) {
            f32x4 a0 = *(const f32x4*)(qp + ks * 32);
            f32x4 a1 = *(const f32x4*)(qp + ks * 32 + 4);
            #pragma unroll
            for (int j = 0; j < 4; ++j) {
                float v0 = a0[j] * scale;
                unsigned short h0 = f2bf(v0);
                qh[ks][j] = (short)h0;
                ql[ks][j] = (short)f2bf(v0 - bf2f(h0));
                float v1 = a1[j] * scale;
                unsigned short h1 = f2bf(v1);
                qh[ks][4 + j] = (short)h1;
                ql[ks][4 + j] = (short)f2bf(v1 - bf2f(h1));
            }
        }
    }

    // dropout mask base (C-layout rows): q = q0+wave*16+4g+r, k = +c
    const float* mbase = mask + (size_t)b * Ssz * Ssz
                       + (size_t)(q0 + wave * 16 + g * 4) * Ssz + c;

    float m_r[4], d_r[4];
    f32x4 acc[4];
    #pragma unroll
    for (int r = 0; r < 4; ++r) { m_r[r] = -INFINITY; d_r[r] = 0.f; }
    #pragma unroll
    for (int n = 0; n < 4; ++n) { f32x4 z = {0.f, 0.f, 0.f, 0.f}; acc[n] = z; }

    // ---- prologue: tile 0 K/V + tile 0 mask into regs
    f32x4 kreg[4], vreg[4];
    #pragma unroll
    for (int i = 0; i < 4; ++i) {
        kreg[i] = *(const f32x4*)(Kb + i * 1024 + tid * 4);
        vreg[i] = *(const f32x4*)(Vb + i * 1024 + tid * 4);
    }
    float mk[4][4];
    #pragma unroll
    for (int tt = 0; tt < 4; ++tt)
        #pragma unroll
        for (int r = 0; r < 4; ++r)
            mk[tt][r] = mbase[(size_t)r * Ssz + 16 * tt];

    for (int t = 0; t < NT; ++t) {
        const int k0 = t * KBLK;

        __syncthreads();   // all waves done reading LDS of previous tile

        // ---- stage K (hi/lo) + V^T from regs into LDS
        #pragma unroll
        for (int i = 0; i < 4; ++i) {
            int fi  = i * 256 + tid;
            int row = fi >> 4;          // key row
            int d0  = (fi & 15) * 4;    // d offset
            u16x4 hv, lv;
            #pragma unroll
            for (int j = 0; j < 4; ++j) {
                float x = kreg[i][j];
                unsigned short h = f2bf(x);
                hv[j] = h;
                lv[j] = f2bf(x - bf2f(h));
            }
            *(u16x4*)(s_khi + swz(row, d0 * 2)) = hv;
            *(u16x4*)(s_klo + swz(row, d0 * 2)) = lv;
            #pragma unroll
            for (int j = 0; j < 4; ++j)     // V transposed, single bf16
                *(unsigned short*)(s_vt + swz(d0 + j, row * 2)) = f2bf(vreg[i][j]);
        }
        __syncthreads();

        // ---- prefetch next tile K/V + mask (issued AFTER barrier so the
        // compiler's vmcnt(0) drain at the barrier can't serialize them;
        // consumed a full tile later -> HBM latency hides under
        // QK^T + softmax + PV + next staging)
        float mk_nxt[4][4];
        if (t + 1 < NT) {
            const float* kp = Kb + (size_t)(k0 + KBLK) * Dsz;
            const float* vp = Vb + (size_t)(k0 + KBLK) * Dsz;
            #pragma unroll
            for (int i = 0; i < 4; ++i) {
                kreg[i] = *(const f32x4*)(kp + i * 1024 + tid * 4);
                vreg[i] = *(const f32x4*)(vp + i * 1024 + tid * 4);
            }
            #pragma unroll
            for (int tt = 0; tt < 4; ++tt)
                #pragma unroll
                for (int r = 0; r < 4; ++r)
                    mk_nxt[tt][r] = mbase[(size_t)r * Ssz + (k0 + KBLK) + 16 * tt];
        }

        // ---- QK^T: hi*hi + hi*lo + lo*hi (3 passes x 2 k-steps)
        f32x4 sv[4];
        __builtin_amdgcn_s_setprio(1);
        #pragma unroll
        for (int tt = 0; tt < 4; ++tt) {
            int rowB = tt * 16 + c;
            short8 kh0 = *(const short8*)(s_khi + swz(rowB, g * 16));
            short8 kh1 = *(const short8*)(s_khi + swz(rowB, 64 + g * 16));
            short8 kl0 = *(const short8*)(s_klo + swz(rowB, g * 16));
            short8 kl1 = *(const short8*)(s_klo + swz(rowB, 64 + g * 16));
            f32x4 a = {0.f, 0.f, 0.f, 0.f};
            a = mfma16(qh[0], kh0, a);
            a = mfma16(qh[1], kh1, a);
            a = mfma16(qh[0], kl0, a);
            a = mfma16(qh[1], kl1, a);
            a = mfma16(ql[0], kh0, a);
            a = mfma16(ql[1], kh1, a);
            sv[tt] = a;
        }
        __builtin_amdgcn_s_setprio(0);

        // ---- online softmax (exp2 domain); row r lives on 16 lanes (same g)
        float corr[4];
        #pragma unroll
        for (int r = 0; r < 4; ++r) {
            float rm = fmaxf(fmaxf(sv[0][r], sv[1][r]), fmaxf(sv[2][r], sv[3][r]));
            rm = fmaxf(rm, __shfl_xor(rm, 1));
            rm = fmaxf(rm, __shfl_xor(rm, 2));
            rm = fmaxf(rm, __shfl_xor(rm, 4));
            rm = fmaxf(rm, __shfl_xor(rm, 8));
            float nm = fmaxf(m_r[r], rm);
            corr[r] = exp2f(m_r[r] - nm);   // first iter: exp2(-inf)=0
            m_r[r] = nm;
        }
        float rs[4] = {0.f, 0.f, 0.f, 0.f};
        float pr[4][4];
        #pragma unroll
        for (int tt = 0; tt < 4; ++tt)
            #pragma unroll
            for (int r = 0; r < 4; ++r) {
                float p = exp2f(sv[tt][r] - m_r[r]);
                rs[r] += p;                                  // denom: pre-dropout
                pr[tt][r] = (mk[tt][r] >= 0.5f) ? 2.0f * p : 0.0f;  // inverted dropout
            }
        #pragma unroll
        for (int r = 0; r < 4; ++r) {
            float s = rs[r];
            s += __shfl_xor(s, 1);
            s += __shfl_xor(s, 2);
            s += __shfl_xor(s, 4);
            s += __shfl_xor(s, 8);
            d_r[r] = d_r[r] * corr[r] + s;
        }
        #pragma unroll
        for (int n = 0; n < 4; ++n)
            #pragma unroll
            for (int r = 0; r < 4; ++r)
                acc[n][r] *= corr[r];

        // ---- rotate mask double-buffer (register moves only; static indices)
        if (t + 1 < NT) {
            #pragma unroll
            for (int tt = 0; tt < 4; ++tt)
                #pragma unroll
                for (int r = 0; r < 4; ++r)
                    mk[tt][r] = mk_nxt[tt][r];
        }

        // ---- P: C-layout regs -> LDS -> A-layout frags (intra-wave, DS in-order)
        #pragma unroll
        for (int tt = 0; tt < 4; ++tt)
            #pragma unroll
            for (int r = 0; r < 4; ++r)
                *(unsigned short*)(s_p + swz(wave * 16 + g * 4 + r, (tt * 16 + c) * 2))
                    = f2bf(pr[tt][r]);

        asm volatile("" ::: "memory");  // no compiler reorder across write->read

        short8 pa0 = *(const short8*)(s_p + swz(wave * 16 + c, g * 16));
        short8 pa1 = *(const short8*)(s_p + swz(wave * 16 + c, 64 + g * 16));
        __builtin_amdgcn_s_setprio(1);
        #pragma unroll
        for (int n = 0; n < 4; ++n) {
            short8 v0 = *(const short8*)(s_vt + swz(n * 16 + c, g * 16));
            short8 v1 = *(const short8*)(s_vt + swz(n * 16 + c, 64 + g * 16));
            acc[n] = mfma16(pa0, v0, acc[n]);
            acc[n] = mfma16(pa1, v1, acc[n]);
        }
        __builtin_amdgcn_s_setprio(0);
    }

    // ---- epilogue: out = acc / denom
    float* ob = out + ((size_t)b * Ssz + (q0 + wave * 16 + g * 4)) * Dsz + c;
    #pragma unroll
    for (int r = 0; r < 4; ++r) {
        float inv = 1.0f / d_r[r];
        #pragma unroll
        for (int n = 0; n < 4; ++n)
            ob[(size_t)r * Dsz + n * 16] = acc[n][r] * inv;
    }
}

extern "C" void kernel_launch(void* const* d_in, const int* in_sizes, int n_in,
                              void* d_out, int out_size, void* d_ws, size_t ws_size,
                              hipStream_t stream)
{
    const float* Q  = (const float*)d_in[0];
    const float* K  = (const float*)d_in[1];
    const float* V  = (const float*)d_in[2];
    const float* sc = (const float*)d_in[3];
    const float* mk = (const float*)d_in[4];
    float* out = (float*)d_out;
    attn_fwd<<<dim3(2048), dim3(256), 0, stream>>>(Q, K, V, sc, mk, out);
}